// Round 12
// baseline (180.878 us; speedup 1.0000x reference)
//
#include <hip/hip_runtime.h>
#include <hip/hip_bf16.h>
#include <math.h>

#define N_POINTS 1000000
#define N_GRIDS  16
#define LOG2_T   19
#define TABLE_MASK ((1u << LOG2_T) - 1u)
#define NBLOCKS  ((N_POINTS + 255) / 256)
#define CONV_BLOCKS 4096
#define FUSED_BLOCKS 2048          // multiple of 8; 8 groups -> 8 XCDs
#define TAILB_BLOCKS 4096
#define N_ENTRIES (N_GRIDS << LOG2_T)   // 8.4M bf16x2 entries
#define NCELL_AX 32                // Morton bucket grid 32^3
#define N_CELLS  (NCELL_AX * NCELL_AX * NCELL_AX)   // 32768

struct ResArr { float r[N_GRIDS]; };

__device__ __forceinline__ unsigned pack_bf16x2(float a, float b)
{
    __hip_bfloat16 ha = __float2bfloat16(a);
    __hip_bfloat16 hb = __float2bfloat16(b);
    unsigned short ua = *(unsigned short*)&ha;
    unsigned short ub = *(unsigned short*)&hb;
    return (unsigned)ua | ((unsigned)ub << 16);
}

__device__ __forceinline__ float2 unpack_bf16x2(unsigned v)
{
    unsigned lo = (v & 0xffffu) << 16;
    unsigned hi = v & 0xffff0000u;
    return make_float2(__uint_as_float(lo), __uint_as_float(hi));
}

// 5-bit -> every-3rd-bit expansion for Morton codes
__device__ __forceinline__ unsigned expand_bits(unsigned v)
{
    v &= 0x3ffu;
    v = (v | (v << 16)) & 0x30000FFu;
    v = (v | (v << 8))  & 0x300F00Fu;
    v = (v | (v << 4))  & 0x30C30C3u;
    v = (v | (v << 2))  & 0x9249249u;
    return v;
}

__device__ __forceinline__ int morton_cell(float x0, float x1, float x2)
{
    int cx = (int)floorf((x0 + 1.f) * 16.f);
    int cy = (int)floorf((x1 + 1.f) * 16.f);
    int cz = (int)floorf((x2 + 1.f) * 16.f);
    cx = min(NCELL_AX - 1, max(0, cx));
    cy = min(NCELL_AX - 1, max(0, cy));
    cz = min(NCELL_AX - 1, max(0, cz));
    return (int)((expand_bits((unsigned)cx) << 2) |
                 (expand_bits((unsigned)cy) << 1) |
                  expand_bits((unsigned)cz));
}

__device__ __forceinline__ unsigned sel4(uint4 P, unsigned idx)
{
    const unsigned lo = (idx & 1u) ? P.y : P.x;
    const unsigned hi = (idx & 1u) ? P.w : P.z;
    return (idx & 2u) ? hi : lo;
}

// gather with uint4 corner-pair loads (R11, measured 82 us @ 5 req/pt-level).
// PRIMES[0]==1 -> x-corner slots {sa, sa^d}, d=v0^(v0+1). d<=3 (75% lanes):
// one uint4 covers both corners; d>=7 lanes add a predicated 4 B load.
// fv content and fma order identical to R2 -> bit-exact results.
__device__ __forceinline__ void gather_level_bf16(
    float x0, float x1, float x2, float r,
    const unsigned* __restrict__ tbl, float& c0, float& c1)
{
    // match reference: (x + 1.0) * 0.5 * r, left-to-right fp32
    const float xn0 = (x0 + 1.0f) * 0.5f * r;
    const float xn1 = (x1 + 1.0f) * 0.5f * r;
    const float xn2 = (x2 + 1.0f) * 0.5f * r;
    const float f0 = floorf(xn0), f1 = floorf(xn1), f2 = floorf(xn2);
    const unsigned v0 = (unsigned)(int)f0;
    const unsigned v1 = (unsigned)(int)f1;
    const unsigned v2 = (unsigned)(int)f2;
    const float w0 = xn0 - f0, w1 = xn1 - f1, w2 = xn2 - f2;
    const unsigned d = v0 ^ (v0 + 1u);     // 2^t - 1

    unsigned sa4[4];
    uint4    pa[4];
    #pragma unroll
    for (int yz = 0; yz < 4; ++yz) {
        const unsigned vy = v1 + ((yz >> 1) & 1);
        const unsigned vz = v2 + (yz & 1);
        const unsigned m  = (vy * 2654435761u) ^ (vz * 805459861u);
        const unsigned sa = (v0 ^ m) & TABLE_MASK;
        sa4[yz] = sa;
        pa[yz]  = ((const uint4*)tbl)[sa >> 2];   // aligned 4-slot group
    }
    const bool far = (d > 3u);             // 25% of lanes
    unsigned ub[4];
    #pragma unroll
    for (int yz = 0; yz < 4; ++yz) {
        unsigned u = 0;
        if (far) u = tbl[(sa4[yz] ^ d) & TABLE_MASK];  // predicated load
        ub[yz] = u;
    }

    unsigned fv[8];
    #pragma unroll
    for (int yz = 0; yz < 4; ++yz) {
        const unsigned ia = sa4[yz] & 3u;
        const unsigned ib = (sa4[yz] ^ d) & 3u;        // valid when !far
        const unsigned uA = sel4(pa[yz], ia);          // slot sa
        const unsigned uB = far ? ub[yz] : sel4(pa[yz], ib);  // slot sa^d
        fv[yz]     = uA;   // k = yz   (x-corner 0)
        fv[4 + yz] = uB;   // k = 4+yz (x-corner 1)
    }

    c0 = 0.f; c1 = 0.f;
    #pragma unroll
    for (int k = 0; k < 8; ++k) {
        const float wgt = ((k & 4) ? w0 : 1.0f - w0) *
                          ((k & 2) ? w1 : 1.0f - w1) *
                          ((k & 1) ? w2 : 1.0f - w2);
        const float2 f = unpack_bf16x2(fv[k]);
        c0 += wgt * f.x;
        c1 += wgt * f.y;
    }
}

// ---- pass 0: fat kernel = table fp32->bf16x2 convert || Morton histogram ---
// conv (BW-bound) overlaps hist (atomic-latency-bound); independent halves.
// Zero-fill moved out of hist into the fused kernel's light groups.
__global__ __launch_bounds__(256)
void prep_kernel(const float* __restrict__ tables, unsigned* __restrict__ tb,
                 const float* __restrict__ x, int* __restrict__ rank,
                 unsigned* __restrict__ hist)
{
    if (blockIdx.x < CONV_BLOCKS) {
        const unsigned nthr = CONV_BLOCKS * 256;
        for (unsigned e4 = blockIdx.x * 256 + threadIdx.x; e4 < (N_ENTRIES / 4);
             e4 += nthr) {
            const float4 a = ((const float4*)tables)[2 * e4];
            const float4 b = ((const float4*)tables)[2 * e4 + 1];
            uint4 o;
            o.x = pack_bf16x2(a.x, a.y);
            o.y = pack_bf16x2(a.z, a.w);
            o.z = pack_bf16x2(b.x, b.y);
            o.w = pack_bf16x2(b.z, b.w);
            ((uint4*)tb)[e4] = o;
        }
    } else {
        const int p = (blockIdx.x - CONV_BLOCKS) * 256 + threadIdx.x;
        if (p >= N_POINTS) return;
        const float x0 = x[3 * p], x1 = x[3 * p + 1], x2 = x[3 * p + 2];
        const bool inbox = (x0 >= -1.f) & (x0 <= 1.f) &
                           (x1 >= -1.f) & (x1 <= 1.f) &
                           (x2 >= -1.f) & (x2 <= 1.f);
        if (inbox) {
            const int cell = morton_cell(x0, x1, x2);
            atomicAdd(&hist[cell], 1u);
            rank[p] = cell;
        } else {
            rank[p] = -1;
        }
    }
}

// ---- pass 0.5: single-block exclusive scan (vectorized uint4 I/O) ----------
__global__ __launch_bounds__(1024)
void scan_kernel(unsigned* __restrict__ hist, unsigned* __restrict__ counter)
{
    __shared__ unsigned partial[1024];
    const int tid = threadIdx.x;
    uint4* __restrict__ hp = (uint4*)hist + tid * 8;   // 32 cells = 8 uint4
    uint4 vv[8];
    unsigned s = 0;
    #pragma unroll
    for (int i = 0; i < 8; ++i) {
        vv[i] = hp[i];
        s += vv[i].x + vv[i].y + vv[i].z + vv[i].w;
    }
    partial[tid] = s;
    __syncthreads();
    for (int off = 1; off < 1024; off <<= 1) {
        unsigned t = (tid >= off) ? partial[tid - off] : 0u;
        __syncthreads();
        partial[tid] += t;
        __syncthreads();
    }
    if (tid == 1023) counter[0] = partial[1023];
    unsigned run = partial[tid] - s;           // exclusive prefix
    #pragma unroll
    for (int i = 0; i < 8; ++i) {
        uint4 o;
        o.x = run; run += vv[i].x;
        o.y = run; run += vv[i].y;
        o.z = run; run += vv[i].z;
        o.w = run; run += vv[i].w;
        hp[i] = o;
    }
}

// ---- pass 0.75: scatter points into Morton-sorted order --------------------
// Thin kernel (conv moved to prep). Stores ORIGINAL point index in xw.w.
__global__ __launch_bounds__(256)
void scatter_kernel(const float* __restrict__ x, const int* __restrict__ rank,
                    float4* __restrict__ xw, unsigned* __restrict__ hist)
{
    const int p = blockIdx.x * 256 + threadIdx.x;
    if (p >= N_POINTS) return;
    const int cell = rank[p];
    if (cell < 0) return;
    const unsigned rk = atomicAdd(&hist[cell], 1u);
    xw[rk] = make_float4(x[3 * p], x[3 * p + 1], x[3 * p + 2],
                         __int_as_float(p));
}

// ---- pass 1: R2-exact schedule + inline zero-fill in LIGHT groups ----------
// 2 levels per XCD group, paired (k,15-k), block-contiguous chunks (best of
// 5 schedule variants). Light groups k<=4 finish early (measured occupancy
// ~48% from drain); after their levels they zero-fill out-of-box output rows
// inline. Unlike R6's trailing-block zf (ran AFTER the grid, +10 us), this
// runs WHILE heavy groups 5-7 still grind -> write channel (idle at ~0.5
// TB/s during fused) absorbs 87 MB for free; makespan (groups 5-7) untouched.
__global__ __launch_bounds__(256)
void fused_levels_kernel(const float4* __restrict__ xw,
                         const unsigned* __restrict__ counter,
                         const unsigned* __restrict__ tb,
                         unsigned* __restrict__ ws2, ResArr res,
                         const int* __restrict__ rank,
                         float* __restrict__ out)
{
    const unsigned k    = blockIdx.x & 7;
    const unsigned bix  = blockIdx.x >> 3;
    const unsigned nbx  = gridDim.x >> 3;
    const unsigned cnt  = *counter;
    const unsigned per  = (cnt + nbx - 1) / nbx;
    const unsigned lo   = bix * per;
    const unsigned hi   = min(cnt, lo + per);

    #pragma unroll 1
    for (int t = 0; t < 2; ++t) {
        const int g = t ? (15 - (int)k) : (int)k;
        const float r = res.r[g];
        const unsigned* __restrict__ tbl = tb + ((size_t)g << LOG2_T);
        unsigned* __restrict__ wrow = ws2 + (size_t)g * N_POINTS;
        for (unsigned i = lo + threadIdx.x; i < hi; i += 256) {
            const float4 v = xw[i];
            float c0, c1;
            gather_level_bf16(v.x, v.y, v.z, r, tbl, c0, c1);
            wrow[i] = pack_bf16x2(c0, c1);
        }
    }

    if (k < 5) {
        // light groups: zero-fill OOB rows. 1280 light blocks partition
        // [0, N_POINTS); each thread zeroes full 128 B rows (burst writes).
        const unsigned li   = k * nbx + bix;           // 0..1279
        const unsigned nli  = 5 * nbx;
        const unsigned zper = (N_POINTS + nli - 1) / nli;
        const unsigned p0   = li * zper;
        const unsigned p1   = min((unsigned)N_POINTS, p0 + zper);
        const float4 z = make_float4(0.f, 0.f, 0.f, 0.f);
        for (unsigned p = p0 + threadIdx.x; p < p1; p += 256) {
            if (rank[p] < 0) {
                float4* __restrict__ row = (float4*)out + (size_t)p * 8;
                #pragma unroll
                for (int i = 0; i < 8; ++i) row[i] = z;
            }
        }
    }
}

// ---- pass 2: sorted-domain tail (part B only) ------------------------------
// Iterate SORTED index -> coalesced ws2 reads; 8 threads/point write the
// 128 B output row contiguously (random writes are fire-and-forget).
__global__ __launch_bounds__(256)
void tail_kernel(const float4* __restrict__ xw,
                 const unsigned* __restrict__ counter,
                 const unsigned* __restrict__ ws2, float* __restrict__ out)
{
    const int t = threadIdx.x;
    const unsigned cnt = *counter;
    const unsigned tot = cnt * 8u;
    for (unsigned tg = blockIdx.x * 256 + t; tg < tot;
         tg += TAILB_BLOCKS * 256) {
        const unsigned i = tg >> 3, q = tg & 7;
        const unsigned a = ws2[(size_t)(2 * q) * N_POINTS + i];
        const unsigned b = ws2[(size_t)(2 * q + 1) * N_POINTS + i];
        const int p = __float_as_int(xw[i].w);
        const float2 fa = unpack_bf16x2(a);
        const float2 fb = unpack_bf16x2(b);
        ((float4*)out)[(size_t)p * 8 + q] =
            make_float4(fa.x, fa.y, fb.x, fb.y);
    }
}

// ---- fallback (ws too small): R1-style monolithic kernel (fp32 tables) -----
__device__ __forceinline__ void gather_level_f32(
    float x0, float x1, float x2, float r,
    const float2* __restrict__ tbl, float& c0, float& c1)
{
    const float xn0 = (x0 + 1.0f) * 0.5f * r;
    const float xn1 = (x1 + 1.0f) * 0.5f * r;
    const float xn2 = (x2 + 1.0f) * 0.5f * r;
    const float f0 = floorf(xn0), f1 = floorf(xn1), f2 = floorf(xn2);
    const unsigned v0 = (unsigned)(int)f0;
    const unsigned v1 = (unsigned)(int)f1;
    const unsigned v2 = (unsigned)(int)f2;
    const float w0 = xn0 - f0, w1 = xn1 - f1, w2 = xn2 - f2;
    c0 = 0.f; c1 = 0.f;
    #pragma unroll
    for (int k = 0; k < 8; ++k) {
        const unsigned vx = v0 + ((k >> 2) & 1);
        const unsigned vy = v1 + ((k >> 1) & 1);
        const unsigned vz = v2 + (k & 1);
        unsigned h = (vx * 1u) ^ (vy * 2654435761u) ^ (vz * 805459861u);
        h &= TABLE_MASK;
        const float wgt = ((k & 4) ? w0 : 1.0f - w0) *
                          ((k & 2) ? w1 : 1.0f - w1) *
                          ((k & 1) ? w2 : 1.0f - w2);
        const float2 f = tbl[h];
        c0 += wgt * f.x;
        c1 += wgt * f.y;
    }
}

__global__ __launch_bounds__(256)
void mono_kernel(const float* __restrict__ x, const float* __restrict__ tables,
                 float* __restrict__ out, ResArr res)
{
    int idx = blockIdx.x * blockDim.x + threadIdx.x;
    if (idx >= N_POINTS * N_GRIDS) return;
    int b = idx >> 4, g = idx & 15;
    float x0 = x[b * 3], x1 = x[b * 3 + 1], x2 = x[b * 3 + 2];
    bool inbox = (x0 >= -1.f) & (x0 <= 1.f) & (x1 >= -1.f) & (x1 <= 1.f) &
                 (x2 >= -1.f) & (x2 <= 1.f);
    float c0 = 0.f, c1 = 0.f;
    if (inbox) {
        const float2* tbl = (const float2*)tables + ((size_t)g << LOG2_T);
        gather_level_f32(x0, x1, x2, res.r[g], tbl, c0, c1);
    }
    ((float2*)out)[(size_t)b * N_GRIDS + g] = make_float2(c0, c1);
}

extern "C" void kernel_launch(void* const* d_in, const int* in_sizes, int n_in,
                              void* d_out, int out_size, void* d_ws, size_t ws_size,
                              hipStream_t stream)
{
    const float* x      = (const float*)d_in[0];
    const float* tables = (const float*)d_in[1];
    float* out          = (float*)d_out;

    ResArr res;
    double pls = exp((log(2048.0) - log(16.0)) / 15.0);
    for (int i = 0; i < N_GRIDS; ++i)
        res.r[i] = (float)floor(16.0 * pow(pls, (double)i));

    // ws layout:
    // [counter 256B][hist 128KB][rank 4MB][xw 16MB][ws2 64MB][tb 33.6MB]
    const size_t off_hist = 256;
    const size_t off_rank = off_hist + (size_t)N_CELLS * 4;
    const size_t off_xw   = off_rank + (size_t)N_POINTS * 4;
    const size_t off_ws2  = off_xw + (size_t)N_POINTS * 16;
    const size_t off_tb   = off_ws2 + (size_t)N_GRIDS * N_POINTS * 4;
    const size_t ws_needed = off_tb + (size_t)N_ENTRIES * 4;

    if (ws_size < ws_needed) {
        int total = N_POINTS * N_GRIDS;
        mono_kernel<<<(total + 255) / 256, 256, 0, stream>>>(x, tables, out, res);
        return;
    }

    char* w = (char*)d_ws;
    unsigned* counter = (unsigned*)w;
    unsigned* hist    = (unsigned*)(w + off_hist);
    int*      rank    = (int*)(w + off_rank);
    float4*   xw      = (float4*)(w + off_xw);
    unsigned* ws2     = (unsigned*)(w + off_ws2);
    unsigned* tb      = (unsigned*)(w + off_tb);

    (void)hipMemsetAsync(w, 0, off_rank, stream);   // counter + hist
    prep_kernel<<<CONV_BLOCKS + NBLOCKS, 256, 0, stream>>>(
        tables, tb, x, rank, hist);
    scan_kernel<<<1, 1024, 0, stream>>>(hist, counter);
    scatter_kernel<<<NBLOCKS, 256, 0, stream>>>(x, rank, xw, hist);
    fused_levels_kernel<<<FUSED_BLOCKS, 256, 0, stream>>>(
        xw, counter, tb, ws2, res, rank, out);
    tail_kernel<<<TAILB_BLOCKS, 256, 0, stream>>>(xw, counter, ws2, out);
}

// Round 13
// 174.365 us; speedup vs baseline: 1.0374x; 1.0374x over previous
//
#include <hip/hip_runtime.h>
#include <hip/hip_bf16.h>
#include <math.h>

#define N_POINTS 1000000
#define N_GRIDS  16
#define LOG2_T   19
#define TABLE_MASK ((1u << LOG2_T) - 1u)
#define NBLOCKS  ((N_POINTS + 255) / 256)
#define CONV_BLOCKS 4096
#define FUSED_BLOCKS 2048          // multiple of 8; 8 groups -> 8 XCDs
#define TAILB_BLOCKS 4096
#define N_ENTRIES (N_GRIDS << LOG2_T)   // 8.4M bf16x2 entries
#define NCELL_AX 32                // Morton bucket grid 32^3
#define N_CELLS  (NCELL_AX * NCELL_AX * NCELL_AX)   // 32768

struct ResArr { float r[N_GRIDS]; };

__device__ __forceinline__ unsigned pack_bf16x2(float a, float b)
{
    __hip_bfloat16 ha = __float2bfloat16(a);
    __hip_bfloat16 hb = __float2bfloat16(b);
    unsigned short ua = *(unsigned short*)&ha;
    unsigned short ub = *(unsigned short*)&hb;
    return (unsigned)ua | ((unsigned)ub << 16);
}

__device__ __forceinline__ float2 unpack_bf16x2(unsigned v)
{
    unsigned lo = (v & 0xffffu) << 16;
    unsigned hi = v & 0xffff0000u;
    return make_float2(__uint_as_float(lo), __uint_as_float(hi));
}

// 5-bit -> every-3rd-bit expansion for Morton codes
__device__ __forceinline__ unsigned expand_bits(unsigned v)
{
    v &= 0x3ffu;
    v = (v | (v << 16)) & 0x30000FFu;
    v = (v | (v << 8))  & 0x300F00Fu;
    v = (v | (v << 4))  & 0x30C30C3u;
    v = (v | (v << 2))  & 0x9249249u;
    return v;
}

__device__ __forceinline__ int morton_cell(float x0, float x1, float x2)
{
    int cx = (int)floorf((x0 + 1.f) * 16.f);
    int cy = (int)floorf((x1 + 1.f) * 16.f);
    int cz = (int)floorf((x2 + 1.f) * 16.f);
    cx = min(NCELL_AX - 1, max(0, cx));
    cy = min(NCELL_AX - 1, max(0, cy));
    cz = min(NCELL_AX - 1, max(0, cz));
    return (int)((expand_bits((unsigned)cx) << 2) |
                 (expand_bits((unsigned)cy) << 1) |
                  expand_bits((unsigned)cz));
}

__device__ __forceinline__ unsigned sel4(uint4 P, unsigned idx)
{
    const unsigned lo = (idx & 1u) ? P.y : P.x;
    const unsigned hi = (idx & 1u) ? P.w : P.z;
    return (idx & 2u) ? hi : lo;
}

// gather with uint4 corner-pair loads (R11, measured 82 us @ 5 req/pt-level).
// PRIMES[0]==1 -> x-corner slots {sa, sa^d}, d=v0^(v0+1). d<=3 (75% lanes):
// one uint4 covers both corners; d>=7 lanes add a predicated 4 B load.
// fv content and fma order identical to R2 -> bit-exact results.
__device__ __forceinline__ void gather_level_bf16(
    float x0, float x1, float x2, float r,
    const unsigned* __restrict__ tbl, float& c0, float& c1)
{
    // match reference: (x + 1.0) * 0.5 * r, left-to-right fp32
    const float xn0 = (x0 + 1.0f) * 0.5f * r;
    const float xn1 = (x1 + 1.0f) * 0.5f * r;
    const float xn2 = (x2 + 1.0f) * 0.5f * r;
    const float f0 = floorf(xn0), f1 = floorf(xn1), f2 = floorf(xn2);
    const unsigned v0 = (unsigned)(int)f0;
    const unsigned v1 = (unsigned)(int)f1;
    const unsigned v2 = (unsigned)(int)f2;
    const float w0 = xn0 - f0, w1 = xn1 - f1, w2 = xn2 - f2;
    const unsigned d = v0 ^ (v0 + 1u);     // 2^t - 1

    unsigned sa4[4];
    uint4    pa[4];
    #pragma unroll
    for (int yz = 0; yz < 4; ++yz) {
        const unsigned vy = v1 + ((yz >> 1) & 1);
        const unsigned vz = v2 + (yz & 1);
        const unsigned m  = (vy * 2654435761u) ^ (vz * 805459861u);
        const unsigned sa = (v0 ^ m) & TABLE_MASK;
        sa4[yz] = sa;
        pa[yz]  = ((const uint4*)tbl)[sa >> 2];   // aligned 4-slot group
    }
    const bool far = (d > 3u);             // 25% of lanes
    unsigned ub[4];
    #pragma unroll
    for (int yz = 0; yz < 4; ++yz) {
        unsigned u = 0;
        if (far) u = tbl[(sa4[yz] ^ d) & TABLE_MASK];  // predicated load
        ub[yz] = u;
    }

    unsigned fv[8];
    #pragma unroll
    for (int yz = 0; yz < 4; ++yz) {
        const unsigned ia = sa4[yz] & 3u;
        const unsigned ib = (sa4[yz] ^ d) & 3u;        // valid when !far
        const unsigned uA = sel4(pa[yz], ia);          // slot sa
        const unsigned uB = far ? ub[yz] : sel4(pa[yz], ib);  // slot sa^d
        fv[yz]     = uA;   // k = yz   (x-corner 0)
        fv[4 + yz] = uB;   // k = 4+yz (x-corner 1)
    }

    c0 = 0.f; c1 = 0.f;
    #pragma unroll
    for (int k = 0; k < 8; ++k) {
        const float wgt = ((k & 4) ? w0 : 1.0f - w0) *
                          ((k & 2) ? w1 : 1.0f - w1) *
                          ((k & 1) ? w2 : 1.0f - w2);
        const float2 f = unpack_bf16x2(fv[k]);
        c0 += wgt * f.x;
        c1 += wgt * f.y;
    }
}

// ---- pass 0: fat kernel = conv || (hist + OOB zero-fill) -------------------
// conv (BW-bound) overlaps hist (atomic-latency-bound). Zero-fill lives in
// the hist branch: its 87 MB of writes fill the write channel while the
// atomics stall, and conv runs on other CUs. (R12 showed zf inside the fused
// gather window costs +24 us via fill-path interference; R10-R12 accounting
// says prep is its cheapest home.)
__global__ __launch_bounds__(256)
void prep_kernel(const float* __restrict__ tables, unsigned* __restrict__ tb,
                 const float* __restrict__ x, int* __restrict__ rank,
                 unsigned* __restrict__ hist, float* __restrict__ out)
{
    if (blockIdx.x < CONV_BLOCKS) {
        const unsigned nthr = CONV_BLOCKS * 256;
        for (unsigned e4 = blockIdx.x * 256 + threadIdx.x; e4 < (N_ENTRIES / 4);
             e4 += nthr) {
            const float4 a = ((const float4*)tables)[2 * e4];
            const float4 b = ((const float4*)tables)[2 * e4 + 1];
            uint4 o;
            o.x = pack_bf16x2(a.x, a.y);
            o.y = pack_bf16x2(a.z, a.w);
            o.z = pack_bf16x2(b.x, b.y);
            o.w = pack_bf16x2(b.z, b.w);
            ((uint4*)tb)[e4] = o;
        }
    } else {
        const int p = (blockIdx.x - CONV_BLOCKS) * 256 + threadIdx.x;
        if (p >= N_POINTS) return;
        const float x0 = x[3 * p], x1 = x[3 * p + 1], x2 = x[3 * p + 2];
        const bool inbox = (x0 >= -1.f) & (x0 <= 1.f) &
                           (x1 >= -1.f) & (x1 <= 1.f) &
                           (x2 >= -1.f) & (x2 <= 1.f);
        if (inbox) {
            const int cell = morton_cell(x0, x1, x2);
            atomicAdd(&hist[cell], 1u);
            rank[p] = cell;
        } else {
            rank[p] = -1;
            float4* __restrict__ row = (float4*)out + (size_t)p * 8;
            const float4 z = make_float4(0.f, 0.f, 0.f, 0.f);
            #pragma unroll
            for (int i = 0; i < 8; ++i) row[i] = z;
        }
    }
}

// ---- pass 0.5: single-block exclusive scan (vectorized uint4 I/O) ----------
__global__ __launch_bounds__(1024)
void scan_kernel(unsigned* __restrict__ hist, unsigned* __restrict__ counter)
{
    __shared__ unsigned partial[1024];
    const int tid = threadIdx.x;
    uint4* __restrict__ hp = (uint4*)hist + tid * 8;   // 32 cells = 8 uint4
    uint4 vv[8];
    unsigned s = 0;
    #pragma unroll
    for (int i = 0; i < 8; ++i) {
        vv[i] = hp[i];
        s += vv[i].x + vv[i].y + vv[i].z + vv[i].w;
    }
    partial[tid] = s;
    __syncthreads();
    for (int off = 1; off < 1024; off <<= 1) {
        unsigned t = (tid >= off) ? partial[tid - off] : 0u;
        __syncthreads();
        partial[tid] += t;
        __syncthreads();
    }
    if (tid == 1023) counter[0] = partial[1023];
    unsigned run = partial[tid] - s;           // exclusive prefix
    #pragma unroll
    for (int i = 0; i < 8; ++i) {
        uint4 o;
        o.x = run; run += vv[i].x;
        o.y = run; run += vv[i].y;
        o.z = run; run += vv[i].z;
        o.w = run; run += vv[i].w;
        hp[i] = o;
    }
}

// ---- pass 0.75: thin scatter into Morton-sorted order ----------------------
// Stores the ORIGINAL point index in xw.w (bit-cast) for the tail.
__global__ __launch_bounds__(256)
void scatter_kernel(const float* __restrict__ x, const int* __restrict__ rank,
                    float4* __restrict__ xw, unsigned* __restrict__ hist)
{
    const int p = blockIdx.x * 256 + threadIdx.x;
    if (p >= N_POINTS) return;
    const int cell = rank[p];
    if (cell < 0) return;
    const unsigned rk = atomicAdd(&hist[cell], 1u);
    xw[rk] = make_float4(x[3 * p], x[3 * p + 1], x[3 * p + 2],
                         __int_as_float(p));
}

// ---- pass 1: R11-exact fused (measured 82 us) ------------------------------
// R2 schedule: 2 levels per XCD group, paired (k,15-k), block-contiguous
// chunks (best of 5 schedule variants). Gather = uint4 corner-pair (5
// req/pt-level; request count is the confirmed currency: 8->6->5 req gave
// 110->93->82 us). No zero-fill here (R12: +24 us interference).
__global__ __launch_bounds__(256)
void fused_levels_kernel(const float4* __restrict__ xw,
                         const unsigned* __restrict__ counter,
                         const unsigned* __restrict__ tb,
                         unsigned* __restrict__ ws2, ResArr res)
{
    const unsigned k    = blockIdx.x & 7;
    const unsigned bix  = blockIdx.x >> 3;
    const unsigned nbx  = gridDim.x >> 3;
    const unsigned cnt  = *counter;
    const unsigned per  = (cnt + nbx - 1) / nbx;
    const unsigned lo   = bix * per;
    const unsigned hi   = min(cnt, lo + per);

    #pragma unroll 1
    for (int t = 0; t < 2; ++t) {
        const int g = t ? (15 - (int)k) : (int)k;
        const float r = res.r[g];
        const unsigned* __restrict__ tbl = tb + ((size_t)g << LOG2_T);
        unsigned* __restrict__ wrow = ws2 + (size_t)g * N_POINTS;
        for (unsigned i = lo + threadIdx.x; i < hi; i += 256) {
            const float4 v = xw[i];
            float c0, c1;
            gather_level_bf16(v.x, v.y, v.z, r, tbl, c0, c1);
            wrow[i] = pack_bf16x2(c0, c1);
        }
    }
}

// ---- pass 2: sorted-domain tail (part B only) ------------------------------
// Iterate SORTED index -> coalesced ws2 reads; 8 threads/point write the
// 128 B output row contiguously (random writes are fire-and-forget).
__global__ __launch_bounds__(256)
void tail_kernel(const float4* __restrict__ xw,
                 const unsigned* __restrict__ counter,
                 const unsigned* __restrict__ ws2, float* __restrict__ out)
{
    const int t = threadIdx.x;
    const unsigned cnt = *counter;
    const unsigned tot = cnt * 8u;
    for (unsigned tg = blockIdx.x * 256 + t; tg < tot;
         tg += TAILB_BLOCKS * 256) {
        const unsigned i = tg >> 3, q = tg & 7;
        const unsigned a = ws2[(size_t)(2 * q) * N_POINTS + i];
        const unsigned b = ws2[(size_t)(2 * q + 1) * N_POINTS + i];
        const int p = __float_as_int(xw[i].w);
        const float2 fa = unpack_bf16x2(a);
        const float2 fb = unpack_bf16x2(b);
        ((float4*)out)[(size_t)p * 8 + q] =
            make_float4(fa.x, fa.y, fb.x, fb.y);
    }
}

// ---- fallback (ws too small): R1-style monolithic kernel (fp32 tables) -----
__device__ __forceinline__ void gather_level_f32(
    float x0, float x1, float x2, float r,
    const float2* __restrict__ tbl, float& c0, float& c1)
{
    const float xn0 = (x0 + 1.0f) * 0.5f * r;
    const float xn1 = (x1 + 1.0f) * 0.5f * r;
    const float xn2 = (x2 + 1.0f) * 0.5f * r;
    const float f0 = floorf(xn0), f1 = floorf(xn1), f2 = floorf(xn2);
    const unsigned v0 = (unsigned)(int)f0;
    const unsigned v1 = (unsigned)(int)f1;
    const unsigned v2 = (unsigned)(int)f2;
    const float w0 = xn0 - f0, w1 = xn1 - f1, w2 = xn2 - f2;
    c0 = 0.f; c1 = 0.f;
    #pragma unroll
    for (int k = 0; k < 8; ++k) {
        const unsigned vx = v0 + ((k >> 2) & 1);
        const unsigned vy = v1 + ((k >> 1) & 1);
        const unsigned vz = v2 + (k & 1);
        unsigned h = (vx * 1u) ^ (vy * 2654435761u) ^ (vz * 805459861u);
        h &= TABLE_MASK;
        const float wgt = ((k & 4) ? w0 : 1.0f - w0) *
                          ((k & 2) ? w1 : 1.0f - w1) *
                          ((k & 1) ? w2 : 1.0f - w2);
        const float2 f = tbl[h];
        c0 += wgt * f.x;
        c1 += wgt * f.y;
    }
}

__global__ __launch_bounds__(256)
void mono_kernel(const float* __restrict__ x, const float* __restrict__ tables,
                 float* __restrict__ out, ResArr res)
{
    int idx = blockIdx.x * blockDim.x + threadIdx.x;
    if (idx >= N_POINTS * N_GRIDS) return;
    int b = idx >> 4, g = idx & 15;
    float x0 = x[b * 3], x1 = x[b * 3 + 1], x2 = x[b * 3 + 2];
    bool inbox = (x0 >= -1.f) & (x0 <= 1.f) & (x1 >= -1.f) & (x1 <= 1.f) &
                 (x2 >= -1.f) & (x2 <= 1.f);
    float c0 = 0.f, c1 = 0.f;
    if (inbox) {
        const float2* tbl = (const float2*)tables + ((size_t)g << LOG2_T);
        gather_level_f32(x0, x1, x2, res.r[g], tbl, c0, c1);
    }
    ((float2*)out)[(size_t)b * N_GRIDS + g] = make_float2(c0, c1);
}

extern "C" void kernel_launch(void* const* d_in, const int* in_sizes, int n_in,
                              void* d_out, int out_size, void* d_ws, size_t ws_size,
                              hipStream_t stream)
{
    const float* x      = (const float*)d_in[0];
    const float* tables = (const float*)d_in[1];
    float* out          = (float*)d_out;

    ResArr res;
    double pls = exp((log(2048.0) - log(16.0)) / 15.0);
    for (int i = 0; i < N_GRIDS; ++i)
        res.r[i] = (float)floor(16.0 * pow(pls, (double)i));

    // ws layout:
    // [counter 256B][hist 128KB][rank 4MB][xw 16MB][ws2 64MB][tb 33.6MB]
    const size_t off_hist = 256;
    const size_t off_rank = off_hist + (size_t)N_CELLS * 4;
    const size_t off_xw   = off_rank + (size_t)N_POINTS * 4;
    const size_t off_ws2  = off_xw + (size_t)N_POINTS * 16;
    const size_t off_tb   = off_ws2 + (size_t)N_GRIDS * N_POINTS * 4;
    const size_t ws_needed = off_tb + (size_t)N_ENTRIES * 4;

    if (ws_size < ws_needed) {
        int total = N_POINTS * N_GRIDS;
        mono_kernel<<<(total + 255) / 256, 256, 0, stream>>>(x, tables, out, res);
        return;
    }

    char* w = (char*)d_ws;
    unsigned* counter = (unsigned*)w;
    unsigned* hist    = (unsigned*)(w + off_hist);
    int*      rank    = (int*)(w + off_rank);
    float4*   xw      = (float4*)(w + off_xw);
    unsigned* ws2     = (unsigned*)(w + off_ws2);
    unsigned* tb      = (unsigned*)(w + off_tb);

    (void)hipMemsetAsync(w, 0, off_rank, stream);   // counter + hist
    prep_kernel<<<CONV_BLOCKS + NBLOCKS, 256, 0, stream>>>(
        tables, tb, x, rank, hist, out);
    scan_kernel<<<1, 1024, 0, stream>>>(hist, counter);
    scatter_kernel<<<NBLOCKS, 256, 0, stream>>>(x, rank, xw, hist);
    fused_levels_kernel<<<FUSED_BLOCKS, 256, 0, stream>>>(xw, counter, tb,
                                                          ws2, res);
    tail_kernel<<<TAILB_BLOCKS, 256, 0, stream>>>(xw, counter, ws2, out);
}

// Round 14
// 173.470 us; speedup vs baseline: 1.0427x; 1.0052x over previous
//
#include <hip/hip_runtime.h>
#include <hip/hip_bf16.h>
#include <math.h>

#define N_POINTS 1000000
#define N_GRIDS  16
#define LOG2_T   19
#define TABLE_MASK ((1u << LOG2_T) - 1u)
#define NBLOCKS  ((N_POINTS + 255) / 256)
#define CONV_BLOCKS 4096
#define FUSED_BLOCKS 2048          // multiple of 8; 8 groups -> 8 XCDs
#define TAILB_BLOCKS 4096
#define N_ENTRIES (N_GRIDS << LOG2_T)   // 8.4M bf16x2 entries
#define NCELL_AX 32                // Morton bucket grid 32^3
#define N_CELLS  (NCELL_AX * NCELL_AX * NCELL_AX)   // 32768

struct ResArr { float r[N_GRIDS]; };

__device__ __forceinline__ unsigned pack_bf16x2(float a, float b)
{
    __hip_bfloat16 ha = __float2bfloat16(a);
    __hip_bfloat16 hb = __float2bfloat16(b);
    unsigned short ua = *(unsigned short*)&ha;
    unsigned short ub = *(unsigned short*)&hb;
    return (unsigned)ua | ((unsigned)ub << 16);
}

__device__ __forceinline__ float2 unpack_bf16x2(unsigned v)
{
    unsigned lo = (v & 0xffffu) << 16;
    unsigned hi = v & 0xffff0000u;
    return make_float2(__uint_as_float(lo), __uint_as_float(hi));
}

// 5-bit -> every-3rd-bit expansion for Morton codes
__device__ __forceinline__ unsigned expand_bits(unsigned v)
{
    v &= 0x3ffu;
    v = (v | (v << 16)) & 0x30000FFu;
    v = (v | (v << 8))  & 0x300F00Fu;
    v = (v | (v << 4))  & 0x30C30C3u;
    v = (v | (v << 2))  & 0x9249249u;
    return v;
}

__device__ __forceinline__ int morton_cell(float x0, float x1, float x2)
{
    int cx = (int)floorf((x0 + 1.f) * 16.f);
    int cy = (int)floorf((x1 + 1.f) * 16.f);
    int cz = (int)floorf((x2 + 1.f) * 16.f);
    cx = min(NCELL_AX - 1, max(0, cx));
    cy = min(NCELL_AX - 1, max(0, cy));
    cz = min(NCELL_AX - 1, max(0, cz));
    return (int)((expand_bits((unsigned)cx) << 2) |
                 (expand_bits((unsigned)cy) << 1) |
                  expand_bits((unsigned)cz));
}

__device__ __forceinline__ unsigned sel4(uint4 P, unsigned idx)
{
    const unsigned lo = (idx & 1u) ? P.y : P.x;
    const unsigned hi = (idx & 1u) ? P.w : P.z;
    return (idx & 2u) ? hi : lo;
}

// gather with uint4 corner-pair loads (R11, measured 82 us @ 5 req/pt-level).
// PRIMES[0]==1 -> x-corner slots {sa, sa^d}, d=v0^(v0+1). d<=3 (75% lanes):
// one uint4 covers both corners; d>=7 lanes add a predicated 4 B load.
// fv content and fma order identical to R2 -> bit-exact results.
__device__ __forceinline__ void gather_level_bf16(
    float x0, float x1, float x2, float r,
    const unsigned* __restrict__ tbl, float& c0, float& c1)
{
    // match reference: (x + 1.0) * 0.5 * r, left-to-right fp32
    const float xn0 = (x0 + 1.0f) * 0.5f * r;
    const float xn1 = (x1 + 1.0f) * 0.5f * r;
    const float xn2 = (x2 + 1.0f) * 0.5f * r;
    const float f0 = floorf(xn0), f1 = floorf(xn1), f2 = floorf(xn2);
    const unsigned v0 = (unsigned)(int)f0;
    const unsigned v1 = (unsigned)(int)f1;
    const unsigned v2 = (unsigned)(int)f2;
    const float w0 = xn0 - f0, w1 = xn1 - f1, w2 = xn2 - f2;
    const unsigned d = v0 ^ (v0 + 1u);     // 2^t - 1

    unsigned sa4[4];
    uint4    pa[4];
    #pragma unroll
    for (int yz = 0; yz < 4; ++yz) {
        const unsigned vy = v1 + ((yz >> 1) & 1);
        const unsigned vz = v2 + (yz & 1);
        const unsigned m  = (vy * 2654435761u) ^ (vz * 805459861u);
        const unsigned sa = (v0 ^ m) & TABLE_MASK;
        sa4[yz] = sa;
        pa[yz]  = ((const uint4*)tbl)[sa >> 2];   // aligned 4-slot group
    }
    const bool far = (d > 3u);             // 25% of lanes
    unsigned ub[4];
    #pragma unroll
    for (int yz = 0; yz < 4; ++yz) {
        unsigned u = 0;
        if (far) u = tbl[(sa4[yz] ^ d) & TABLE_MASK];  // predicated load
        ub[yz] = u;
    }

    unsigned fv[8];
    #pragma unroll
    for (int yz = 0; yz < 4; ++yz) {
        const unsigned ia = sa4[yz] & 3u;
        const unsigned ib = (sa4[yz] ^ d) & 3u;        // valid when !far
        const unsigned uA = sel4(pa[yz], ia);          // slot sa
        const unsigned uB = far ? ub[yz] : sel4(pa[yz], ib);  // slot sa^d
        fv[yz]     = uA;   // k = yz   (x-corner 0)
        fv[4 + yz] = uB;   // k = 4+yz (x-corner 1)
    }

    c0 = 0.f; c1 = 0.f;
    #pragma unroll
    for (int k = 0; k < 8; ++k) {
        const float wgt = ((k & 4) ? w0 : 1.0f - w0) *
                          ((k & 2) ? w1 : 1.0f - w1) *
                          ((k & 1) ? w2 : 1.0f - w2);
        const float2 f = unpack_bf16x2(fv[k]);
        c0 += wgt * f.x;
        c1 += wgt * f.y;
    }
}

// ---- pass 0: fat kernel = conv || hist (no zero-fill here) -----------------
// conv (BW-bound) overlaps hist (atomic-latency-bound). zf placement ledger:
// tail-A +12us (R10), hist-standalone +5.5 (R11), fused-inline +24 (R12),
// prep-hist +17.5 (R13: conv already saturates prep's BW -> purely additive).
// -> zf now lives in scatter (idle BW + latency-bound + before gather window).
__global__ __launch_bounds__(256)
void prep_kernel(const float* __restrict__ tables, unsigned* __restrict__ tb,
                 const float* __restrict__ x, int* __restrict__ rank,
                 unsigned* __restrict__ hist)
{
    if (blockIdx.x < CONV_BLOCKS) {
        const unsigned nthr = CONV_BLOCKS * 256;
        for (unsigned e4 = blockIdx.x * 256 + threadIdx.x; e4 < (N_ENTRIES / 4);
             e4 += nthr) {
            const float4 a = ((const float4*)tables)[2 * e4];
            const float4 b = ((const float4*)tables)[2 * e4 + 1];
            uint4 o;
            o.x = pack_bf16x2(a.x, a.y);
            o.y = pack_bf16x2(a.z, a.w);
            o.z = pack_bf16x2(b.x, b.y);
            o.w = pack_bf16x2(b.z, b.w);
            ((uint4*)tb)[e4] = o;
        }
    } else {
        const int p = (blockIdx.x - CONV_BLOCKS) * 256 + threadIdx.x;
        if (p >= N_POINTS) return;
        const float x0 = x[3 * p], x1 = x[3 * p + 1], x2 = x[3 * p + 2];
        const bool inbox = (x0 >= -1.f) & (x0 <= 1.f) &
                           (x1 >= -1.f) & (x1 <= 1.f) &
                           (x2 >= -1.f) & (x2 <= 1.f);
        if (inbox) {
            const int cell = morton_cell(x0, x1, x2);
            atomicAdd(&hist[cell], 1u);
            rank[p] = cell;
        } else {
            rank[p] = -1;
        }
    }
}

// ---- pass 0.5: single-block exclusive scan (vectorized uint4 I/O) ----------
__global__ __launch_bounds__(1024)
void scan_kernel(unsigned* __restrict__ hist, unsigned* __restrict__ counter)
{
    __shared__ unsigned partial[1024];
    const int tid = threadIdx.x;
    uint4* __restrict__ hp = (uint4*)hist + tid * 8;   // 32 cells = 8 uint4
    uint4 vv[8];
    unsigned s = 0;
    #pragma unroll
    for (int i = 0; i < 8; ++i) {
        vv[i] = hp[i];
        s += vv[i].x + vv[i].y + vv[i].z + vv[i].w;
    }
    partial[tid] = s;
    __syncthreads();
    for (int off = 1; off < 1024; off <<= 1) {
        unsigned t = (tid >= off) ? partial[tid - off] : 0u;
        __syncthreads();
        partial[tid] += t;
        __syncthreads();
    }
    if (tid == 1023) counter[0] = partial[1023];
    unsigned run = partial[tid] - s;           // exclusive prefix
    #pragma unroll
    for (int i = 0; i < 8; ++i) {
        uint4 o;
        o.x = run; run += vv[i].x;
        o.y = run; run += vv[i].y;
        o.z = run; run += vv[i].z;
        o.w = run; run += vv[i].w;
        hp[i] = o;
    }
}

// ---- pass 0.75: scatter + OOB zero-fill ------------------------------------
// In-box lanes: atomic rank + 16 B xw write (latency-bound, ~3 us of traffic
// on a ~12 us runtime). OOB lanes (682k) were idle after inst 3 -> they now
// write their 128 B zero row; the 87 MB rides the idle write channel while
// in-box lanes stall on atomics. Runs BEFORE the gather window (no fill-path
// interference, unlike R12's fused-inline zf).
__global__ __launch_bounds__(256)
void scatter_kernel(const float* __restrict__ x, const int* __restrict__ rank,
                    float4* __restrict__ xw, unsigned* __restrict__ hist,
                    float* __restrict__ out)
{
    const int p = blockIdx.x * 256 + threadIdx.x;
    if (p >= N_POINTS) return;
    const int cell = rank[p];
    if (cell < 0) {
        float4* __restrict__ row = (float4*)out + (size_t)p * 8;
        const float4 z = make_float4(0.f, 0.f, 0.f, 0.f);
        #pragma unroll
        for (int i = 0; i < 8; ++i) row[i] = z;
        return;
    }
    const unsigned rk = atomicAdd(&hist[cell], 1u);
    xw[rk] = make_float4(x[3 * p], x[3 * p + 1], x[3 * p + 2],
                         __int_as_float(p));
}

// ---- pass 1: R11-exact fused (measured 82 us) ------------------------------
// R2 schedule: 2 levels per XCD group, paired (k,15-k), block-contiguous
// chunks (best of 5 schedule variants). Gather = uint4 corner-pair (5
// req/pt-level; request count is the confirmed currency: 8->6->5 req gave
// 110->93->82 us). No zero-fill here (R12: +24 us interference).
__global__ __launch_bounds__(256)
void fused_levels_kernel(const float4* __restrict__ xw,
                         const unsigned* __restrict__ counter,
                         const unsigned* __restrict__ tb,
                         unsigned* __restrict__ ws2, ResArr res)
{
    const unsigned k    = blockIdx.x & 7;
    const unsigned bix  = blockIdx.x >> 3;
    const unsigned nbx  = gridDim.x >> 3;
    const unsigned cnt  = *counter;
    const unsigned per  = (cnt + nbx - 1) / nbx;
    const unsigned lo   = bix * per;
    const unsigned hi   = min(cnt, lo + per);

    #pragma unroll 1
    for (int t = 0; t < 2; ++t) {
        const int g = t ? (15 - (int)k) : (int)k;
        const float r = res.r[g];
        const unsigned* __restrict__ tbl = tb + ((size_t)g << LOG2_T);
        unsigned* __restrict__ wrow = ws2 + (size_t)g * N_POINTS;
        for (unsigned i = lo + threadIdx.x; i < hi; i += 256) {
            const float4 v = xw[i];
            float c0, c1;
            gather_level_bf16(v.x, v.y, v.z, r, tbl, c0, c1);
            wrow[i] = pack_bf16x2(c0, c1);
        }
    }
}

// ---- pass 2: sorted-domain tail (part B only) ------------------------------
// Iterate SORTED index -> coalesced ws2 reads; 8 threads/point write the
// 128 B output row contiguously (random writes are fire-and-forget).
__global__ __launch_bounds__(256)
void tail_kernel(const float4* __restrict__ xw,
                 const unsigned* __restrict__ counter,
                 const unsigned* __restrict__ ws2, float* __restrict__ out)
{
    const int t = threadIdx.x;
    const unsigned cnt = *counter;
    const unsigned tot = cnt * 8u;
    for (unsigned tg = blockIdx.x * 256 + t; tg < tot;
         tg += TAILB_BLOCKS * 256) {
        const unsigned i = tg >> 3, q = tg & 7;
        const unsigned a = ws2[(size_t)(2 * q) * N_POINTS + i];
        const unsigned b = ws2[(size_t)(2 * q + 1) * N_POINTS + i];
        const int p = __float_as_int(xw[i].w);
        const float2 fa = unpack_bf16x2(a);
        const float2 fb = unpack_bf16x2(b);
        ((float4*)out)[(size_t)p * 8 + q] =
            make_float4(fa.x, fa.y, fb.x, fb.y);
    }
}

// ---- fallback (ws too small): R1-style monolithic kernel (fp32 tables) -----
__device__ __forceinline__ void gather_level_f32(
    float x0, float x1, float x2, float r,
    const float2* __restrict__ tbl, float& c0, float& c1)
{
    const float xn0 = (x0 + 1.0f) * 0.5f * r;
    const float xn1 = (x1 + 1.0f) * 0.5f * r;
    const float xn2 = (x2 + 1.0f) * 0.5f * r;
    const float f0 = floorf(xn0), f1 = floorf(xn1), f2 = floorf(xn2);
    const unsigned v0 = (unsigned)(int)f0;
    const unsigned v1 = (unsigned)(int)f1;
    const unsigned v2 = (unsigned)(int)f2;
    const float w0 = xn0 - f0, w1 = xn1 - f1, w2 = xn2 - f2;
    c0 = 0.f; c1 = 0.f;
    #pragma unroll
    for (int k = 0; k < 8; ++k) {
        const unsigned vx = v0 + ((k >> 2) & 1);
        const unsigned vy = v1 + ((k >> 1) & 1);
        const unsigned vz = v2 + (k & 1);
        unsigned h = (vx * 1u) ^ (vy * 2654435761u) ^ (vz * 805459861u);
        h &= TABLE_MASK;
        const float wgt = ((k & 4) ? w0 : 1.0f - w0) *
                          ((k & 2) ? w1 : 1.0f - w1) *
                          ((k & 1) ? w2 : 1.0f - w2);
        const float2 f = tbl[h];
        c0 += wgt * f.x;
        c1 += wgt * f.y;
    }
}

__global__ __launch_bounds__(256)
void mono_kernel(const float* __restrict__ x, const float* __restrict__ tables,
                 float* __restrict__ out, ResArr res)
{
    int idx = blockIdx.x * blockDim.x + threadIdx.x;
    if (idx >= N_POINTS * N_GRIDS) return;
    int b = idx >> 4, g = idx & 15;
    float x0 = x[b * 3], x1 = x[b * 3 + 1], x2 = x[b * 3 + 2];
    bool inbox = (x0 >= -1.f) & (x0 <= 1.f) & (x1 >= -1.f) & (x1 <= 1.f) &
                 (x2 >= -1.f) & (x2 <= 1.f);
    float c0 = 0.f, c1 = 0.f;
    if (inbox) {
        const float2* tbl = (const float2*)tables + ((size_t)g << LOG2_T);
        gather_level_f32(x0, x1, x2, res.r[g], tbl, c0, c1);
    }
    ((float2*)out)[(size_t)b * N_GRIDS + g] = make_float2(c0, c1);
}

extern "C" void kernel_launch(void* const* d_in, const int* in_sizes, int n_in,
                              void* d_out, int out_size, void* d_ws, size_t ws_size,
                              hipStream_t stream)
{
    const float* x      = (const float*)d_in[0];
    const float* tables = (const float*)d_in[1];
    float* out          = (float*)d_out;

    ResArr res;
    double pls = exp((log(2048.0) - log(16.0)) / 15.0);
    for (int i = 0; i < N_GRIDS; ++i)
        res.r[i] = (float)floor(16.0 * pow(pls, (double)i));

    // ws layout:
    // [counter 256B][hist 128KB][rank 4MB][xw 16MB][ws2 64MB][tb 33.6MB]
    const size_t off_hist = 256;
    const size_t off_rank = off_hist + (size_t)N_CELLS * 4;
    const size_t off_xw   = off_rank + (size_t)N_POINTS * 4;
    const size_t off_ws2  = off_xw + (size_t)N_POINTS * 16;
    const size_t off_tb   = off_ws2 + (size_t)N_GRIDS * N_POINTS * 4;
    const size_t ws_needed = off_tb + (size_t)N_ENTRIES * 4;

    if (ws_size < ws_needed) {
        int total = N_POINTS * N_GRIDS;
        mono_kernel<<<(total + 255) / 256, 256, 0, stream>>>(x, tables, out, res);
        return;
    }

    char* w = (char*)d_ws;
    unsigned* counter = (unsigned*)w;
    unsigned* hist    = (unsigned*)(w + off_hist);
    int*      rank    = (int*)(w + off_rank);
    float4*   xw      = (float4*)(w + off_xw);
    unsigned* ws2     = (unsigned*)(w + off_ws2);
    unsigned* tb      = (unsigned*)(w + off_tb);

    (void)hipMemsetAsync(w, 0, off_rank, stream);   // counter + hist
    prep_kernel<<<CONV_BLOCKS + NBLOCKS, 256, 0, stream>>>(
        tables, tb, x, rank, hist);
    scan_kernel<<<1, 1024, 0, stream>>>(hist, counter);
    scatter_kernel<<<NBLOCKS, 256, 0, stream>>>(x, rank, xw, hist, out);
    fused_levels_kernel<<<FUSED_BLOCKS, 256, 0, stream>>>(xw, counter, tb,
                                                          ws2, res);
    tail_kernel<<<TAILB_BLOCKS, 256, 0, stream>>>(xw, counter, ws2, out);
}